// Round 2
// baseline (185.142 us; speedup 1.0000x reference)
//
#include <hip/hip_runtime.h>

#define NPG  256   // nodes per graph
#define EPG  4096  // edges per graph
#define FDIM 128
#define KTOP 30

// LDS budget kept < 64 KB (55.5 KB) so the launch is valid under the classic
// per-workgroup limit. Z features live in registers (thread t owns node t).
__global__ __launch_bounds__(256, 1)
void dgcnn_fused(const float* __restrict__ node_feat,
                 const int* __restrict__ srcv, const int* __restrict__ dstv,
                 const int* __restrict__ degs,
                 const float* __restrict__ W0, const float* __restrict__ b0,
                 const float* __restrict__ W1, const float* __restrict__ b1,
                 const float* __restrict__ W2, const float* __restrict__ b2,
                 const float* __restrict__ W3, const float* __restrict__ b3,
                 const float* __restrict__ cw1, const float* __restrict__ cb1,
                 const float* __restrict__ cw2, const float* __restrict__ cb2,
                 const float* __restrict__ ow,  const float* __restrict__ ob,
                 float* __restrict__ outp)
{
    __shared__ float Ybuf[NPG * 33];   // 33792 B; stride 33 -> bank (n+c)%32
    __shared__ int   srclist[EPG];     // 16384 B; in-edges grouped by dst; reused by tail
    __shared__ int   offs[NPG];
    __shared__ int   cnt [NPG];
    __shared__ int   degl[NPG];
    __shared__ float invd[NPG];
    __shared__ float keys[NPG];
    __shared__ int   sel [KTOP + 2];
    // total ~55.5 KB

    const int g = blockIdx.x;
    const int t = threadIdx.x;

    // ================= edge-list build (counting sort by dst) =================
    int dn = degs[g * NPG + t];
    degl[t] = dn;
    cnt[t]  = 0;
    invd[t] = 1.0f / (float)(dn + 1);
    offs[t] = dn;
    __syncthreads();
    for (int s = 1; s < NPG; s <<= 1) {
        int v = (t >= s) ? offs[t - s] : 0;
        __syncthreads();
        offs[t] += v;
        __syncthreads();
    }
    int excl = offs[t] - dn;   // exclusive prefix of in-degrees
    __syncthreads();
    offs[t] = excl;
    __syncthreads();
    {
        const int* sg = srcv + g * EPG;
        const int* dg = dstv + g * EPG;
        for (int i = 0; i < EPG / NPG; i++) {
            int e  = t + i * NPG;
            int ss = sg[e] & (NPG - 1);   // graphs are 256-node aligned
            int dd = dg[e] & (NPG - 1);
            int p  = atomicAdd(&cnt[dd], 1);
            srclist[offs[dd] + p] = ss;
        }
    }

    // ================= phase 0: y0 = node_feat @ W0 =================
    float acc[32];
    #pragma unroll
    for (int c = 0; c < 32; c++) acc[c] = 0.f;
    {
        const float* nf = node_feat + (size_t)g * NPG * FDIM;
        for (int kc = 0; kc < 4; kc++) {
            __syncthreads();   // Ybuf chunk reuse
            // stage [256 nodes x 32 k] coalesced into Ybuf (stride 33)
            #pragma unroll
            for (int i = 0; i < 8; i++) {
                int Fi = t + i * 256;
                int n  = Fi >> 3, k4 = Fi & 7;
                const float4 v = *(const float4*)(nf + n * FDIM + kc * 32 + k4 * 4);
                float* p = &Ybuf[n * 33 + k4 * 4];
                p[0] = v.x; p[1] = v.y; p[2] = v.z; p[3] = v.w;
            }
            __syncthreads();
            #pragma unroll
            for (int k = 0; k < 32; k++) {
                float h = Ybuf[t * 33 + k];                // bank (t+k)%32: conflict-free
                const float* wr = W0 + (kc * 32 + k) * 32; // wave-uniform -> scalar loads
                #pragma unroll
                for (int c = 0; c < 32; c++) acc[c] = fmaf(h, wr[c], acc[c]);
            }
        }
        __syncthreads();
        #pragma unroll
        for (int c = 0; c < 32; c++) Ybuf[t * 33 + c] = acc[c];
        __syncthreads();
    }

    float h1[32], h2[32], h3[32];
    const float iv = invd[t];
    const int   o  = offs[t];
    const int   d  = degl[t];

    // pooled = y[t] + sum_{in-edges} y[src]  (whole 32-wide rows from Ybuf)
    auto agg = [&](float (&h)[32]) {
        #pragma unroll
        for (int c = 0; c < 32; c++) h[c] = Ybuf[t * 33 + c];   // self term
        for (int j = 0; j < d; j++) {
            int a = srclist[o + j];
            const float* yr = &Ybuf[a * 33];
            #pragma unroll
            for (int c = 0; c < 32; c++) h[c] += yr[c];
        }
    };
    auto act = [&](float (&h)[32], const float* bb) {
        #pragma unroll
        for (int c = 0; c < 32; c++) h[c] = tanhf((h[c] + bb[c]) * iv);
    };
    // y_next = h @ Wn (32x32) -> Ybuf (barrier-protected overwrite)
    auto matml = [&](const float (&h)[32], const float* Wn) {
        float a[32];
        #pragma unroll
        for (int c = 0; c < 32; c++) a[c] = 0.f;
        #pragma unroll
        for (int k = 0; k < 32; k++) {
            const float* wr = Wn + k * 32;   // uniform -> scalar loads
            float hk = h[k];
            #pragma unroll
            for (int c = 0; c < 32; c++) a[c] = fmaf(hk, wr[c], a[c]);
        }
        __syncthreads();   // all agg reads of Ybuf complete
        #pragma unroll
        for (int c = 0; c < 32; c++) Ybuf[t * 33 + c] = a[c];
        __syncthreads();
    };

    // ================= 4 GNN layers =================
    agg(h1); act(h1, b0); matml(h1, W1);
    agg(h2); act(h2, b1); matml(h2, W2);
    agg(h3); act(h3, b2);
    {   // layer 3 projection: y3 = h3 @ W3  (W3 is 32x1)
        float a3 = 0.f;
        #pragma unroll
        for (int k = 0; k < 32; k++) a3 = fmaf(h3[k], W3[k], a3);
        __syncthreads();   // all layer-2 agg reads of Ybuf complete
        Ybuf[t * 33] = a3;
        __syncthreads();
    }
    float kv;
    {   // layer 3 aggregate (1-wide) + activation -> sort key
        float s = Ybuf[t * 33];
        for (int j = 0; j < d; j++) s += Ybuf[srclist[o + j] * 33];
        kv = tanhf((s + b3[0]) * iv);
        keys[t] = kv;
    }
    __syncthreads();

    // ================= sortpool: rank-based top-K (jax tie-break: lower idx) ====
    int rank = 0;
    #pragma unroll 4
    for (int j = 0; j < NPG; j++) {
        float vj = keys[j];
        rank += ((vj > kv) || ((vj == kv) && (j < t))) ? 1 : 0;
    }
    if (rank < KTOP) sel[rank] = t;
    __syncthreads();

    // ================= export selected Z rows, then conv tail =================
    float* sp    = (float*)srclist;   // 2910 floats
    float* x1    = sp + 30 * 97;      // 480
    float* xp    = x1 + 480;          // 240
    float* dense = xp + 240;          // 352  (total 3982 floats <= 4096)

    if (rank < KTOP) {
        float* dp = sp + rank * 97;
        #pragma unroll
        for (int c = 0; c < 32; c++) dp[c]      = h1[c];
        #pragma unroll
        for (int c = 0; c < 32; c++) dp[32 + c] = h2[c];
        #pragma unroll
        for (int c = 0; c < 32; c++) dp[64 + c] = h3[c];
        dp[96] = kv;
    }
    __syncthreads();

    // conv1: kernel width 97, stride 97 -> per-row dot; out [16][30], relu
    for (int idx = t; idx < 480; idx += 256) {
        int k = idx >> 4, c = idx & 15;
        float s = cb1[c];
        for (int dd = 0; dd < 97; dd++) s = fmaf(sp[k * 97 + dd], cw1[c * 97 + dd], s);
        x1[c * 30 + k] = fmaxf(s, 0.f);
    }
    __syncthreads();
    // maxpool1d(2,2) -> [16][15]
    for (int idx = t; idx < 240; idx += 256) {
        int c = idx / 15, k = idx - c * 15;
        xp[idx] = fmaxf(x1[c * 30 + 2 * k], x1[c * 30 + 2 * k + 1]);
    }
    __syncthreads();
    // conv2: [32][16][5] VALID over 15 -> [32][11], relu; dense idx = c*11+j
    for (int idx = t; idx < 352; idx += 256) {
        int c = idx / 11, j = idx - c * 11;
        float s = cb2[c];
        for (int i2 = 0; i2 < 16; i2++) {
            #pragma unroll
            for (int tt = 0; tt < 5; tt++)
                s = fmaf(xp[i2 * 15 + j + tt], cw2[(c * 16 + i2) * 5 + tt], s);
        }
        dense[idx] = fmaxf(s, 0.f);
    }
    __syncthreads();
    // output: relu(relu(dense @ out_w + out_b)) -> [2]
    if (t < 64) {
        float a0 = 0.f, a1 = 0.f;
        for (int dd = t; dd < 352; dd += 64) {
            float v = dense[dd];
            a0 = fmaf(v, ow[dd * 2],     a0);
            a1 = fmaf(v, ow[dd * 2 + 1], a1);
        }
        #pragma unroll
        for (int off2 = 32; off2 > 0; off2 >>= 1) {
            a0 += __shfl_down(a0, off2);
            a1 += __shfl_down(a1, off2);
        }
        if (t == 0) {
            outp[g * 2 + 0] = fmaxf(a0 + ob[0], 0.f);
            outp[g * 2 + 1] = fmaxf(a1 + ob[1], 0.f);
        }
    }
}

extern "C" void kernel_launch(void* const* d_in, const int* in_sizes, int n_in,
                              void* d_out, int out_size, void* d_ws, size_t ws_size,
                              hipStream_t stream) {
    const float* node_feat = (const float*)d_in[0];
    const int*   src       = (const int*)  d_in[1];
    const int*   dst       = (const int*)  d_in[2];
    const int*   degsp     = (const int*)  d_in[3];
    const float* W0 = (const float*)d_in[4];
    const float* b0 = (const float*)d_in[5];
    const float* W1 = (const float*)d_in[6];
    const float* b1 = (const float*)d_in[7];
    const float* W2 = (const float*)d_in[8];
    const float* b2 = (const float*)d_in[9];
    const float* W3 = (const float*)d_in[10];
    const float* b3 = (const float*)d_in[11];
    const float* cw1 = (const float*)d_in[12];
    const float* cb1 = (const float*)d_in[13];
    const float* cw2 = (const float*)d_in[14];
    const float* cb2 = (const float*)d_in[15];
    const float* ow  = (const float*)d_in[16];
    const float* ob  = (const float*)d_in[17];

    dgcnn_fused<<<dim3(256), dim3(256), 0, stream>>>(
        node_feat, src, dst, degsp,
        W0, b0, W1, b1, W2, b2, W3, b3,
        cw1, cb1, cw2, cb2, ow, ob, (float*)d_out);
}